// Round 6
// baseline (266.476 us; speedup 1.0000x reference)
//
#include <hip/hip_runtime.h>
#include <stdint.h>

#define NTOK 8192   // B*T
#define D 1024
#define E 8
#define BM 128
#define BN 128
#define BK 64

typedef __attribute__((ext_vector_type(8))) short short8;
typedef __attribute__((ext_vector_type(4))) float f32x4;

// fp32 -> bf16 bits, round-to-nearest-even
__device__ __forceinline__ ushort f2bf(float f) {
  uint32_t x = __float_as_uint(f);
  x += 0x7FFFu + ((x >> 16) & 1u);
  return (ushort)(x >> 16);
}

#define NW4 2097152   // E*D*D/4
#define ND4 2097152   // NTOK*D/4
#define NO4 2097152   // NTOK*D/4 (out, float4)
#define CONV_BLOCKS ((NW4 + ND4 + NO4) / 256)   // 24576
#define GATE_BLOCKS (NTOK / 4)                  // 2048

// Fused pre-pass (ONE dispatch): convert expert_W->bf16, delta->bf16,
// zero out + cnt, AND compute gating top-2 (blocks >= CONV_BLOCKS).
__global__ __launch_bounds__(256) void fused_pre_kernel(
    const float* __restrict__ expert_W, const float* __restrict__ delta,
    const float* __restrict__ x, const float* __restrict__ gW,
    const float* __restrict__ gb,
    ushort* __restrict__ Wb, ushort* __restrict__ Db,
    float* __restrict__ out, int* __restrict__ cnt,
    int* __restrict__ idx01, float2* __restrict__ w01) {
  int b = blockIdx.x;
  if (b < CONV_BLOCKS) {
    int i = b * 256 + threadIdx.x;
    if (i < E) cnt[i] = 0;
    if (i < NW4) {
      float4 v = ((const float4*)expert_W)[i];
      ushort4 u; u.x = f2bf(v.x); u.y = f2bf(v.y); u.z = f2bf(v.z); u.w = f2bf(v.w);
      ((ushort4*)Wb)[i] = u;
    } else if (i < NW4 + ND4) {
      int j = i - NW4;
      float4 v = ((const float4*)delta)[j];
      ushort4 u; u.x = f2bf(v.x); u.y = f2bf(v.y); u.z = f2bf(v.z); u.w = f2bf(v.w);
      ((ushort4*)Db)[j] = u;
    } else {
      ((float4*)out)[i - NW4 - ND4] = (float4){0.f, 0.f, 0.f, 0.f};
    }
    return;
  }
  // ---- gating: wave per token, fp32 logits, top-2, softmax ----
  int wave = threadIdx.x >> 6;
  int lane = threadIdx.x & 63;
  int t = (b - CONV_BLOCKS) * 4 + wave;

  const float4* xr = (const float4*)(x + (size_t)t * D) + lane * 4;
  float acc[E];
#pragma unroll
  for (int e = 0; e < E; ++e) acc[e] = 0.f;
#pragma unroll
  for (int q = 0; q < 4; ++q) {
    float4 xv = xr[q];
#pragma unroll
    for (int e = 0; e < E; ++e) {
      float4 wv = ((const float4*)(gW + e * D))[lane * 4 + q];
      acc[e] += xv.x * wv.x + xv.y * wv.y + xv.z * wv.z + xv.w * wv.w;
    }
  }
#pragma unroll
  for (int e = 0; e < E; ++e) {
    float v = acc[e];
#pragma unroll
    for (int off = 32; off > 0; off >>= 1) v += __shfl_xor(v, off, 64);
    acc[e] = v;
  }
  if (lane == 0) {
    float lg[E];
#pragma unroll
    for (int e = 0; e < E; ++e) lg[e] = acc[e] + gb[e];
    int i0 = 0; float v0 = lg[0];
#pragma unroll
    for (int e = 1; e < E; ++e) { if (lg[e] > v0) { v0 = lg[e]; i0 = e; } }
    int i1 = -1; float v1 = -1e30f;
#pragma unroll
    for (int e = 0; e < E; ++e) { if (e != i0 && lg[e] > v1) { v1 = lg[e]; i1 = e; } }
    float e1 = __expf(v1 - v0);
    float inv = 1.f / (1.f + e1);
    idx01[t] = i0 | (i1 << 16);
    w01[t] = make_float2(inv, e1 * inv);
  }
}

// Counting-sort into per-expert lists. LDS histogram, 8 global atomics/block.
__global__ __launch_bounds__(256) void bin_kernel(
    const int* __restrict__ idx01, const float2* __restrict__ w01,
    int* __restrict__ cnt, int* __restrict__ list, float* __restrict__ wlist) {
  __shared__ int hist[E];
  __shared__ int base[E];
  int tid = threadIdx.x;
  int t = blockIdx.x * 256 + tid;
  if (tid < E) hist[tid] = 0;
  __syncthreads();

  int packed = idx01[t];
  float2 w = w01[t];
  int i0 = packed & 0xFFFF, i1 = packed >> 16;
  int r0 = atomicAdd(&hist[i0], 1);
  int r1 = atomicAdd(&hist[i1], 1);
  __syncthreads();
  if (tid < E) base[tid] = atomicAdd(&cnt[tid], hist[tid]);
  __syncthreads();

  int s0 = base[i0] + r0;
  list[i0 * NTOK + s0] = t; wlist[i0 * NTOK + s0] = w.x;
  int s1 = base[i1] + r1;
  list[i1 * NTOK + s1] = t; wlist[i1 * NTOK + s1] = w.y;
}

// Grouped GEMM v3: BM=128,BN=128,BK=64 -> 32 MFMA per barrier (2x v2
// intensity), A re-fetch halved. XOR-swizzled LDS (conflict-free, measured 0
// in v2). XCD-affine: bx&7 == e -> each XCD's 4MB L2 holds one expert's 2MB
// W, so B staging drains from L2 not LLC. ~1050 working blocks at 4/CU
// (launch_bounds caps VGPR so LDS 32KB is the only residency limit).
__global__ __launch_bounds__(256, 4) void moe_gemm_kernel(
    const ushort* __restrict__ Db, const ushort* __restrict__ Wb,
    const float* __restrict__ eb, const int* __restrict__ cnt,
    const int* __restrict__ list, const float* __restrict__ wlist,
    float* __restrict__ out) {
  int bx = blockIdx.x;
  int e = bx & 7;          // XCD-affine
  int nt = (bx >> 3) & 7;
  int mt = bx >> 6;
  int M = cnt[e];
  int m0 = mt * BM;
  if (m0 >= M) return;
  int n0 = nt * BN;

  __shared__ ushort As[BM * BK];  // 16 KB, row = 64 elem = 8 granules
  __shared__ ushort Bs[BN * BK];  // 16 KB

  int tid = threadIdx.x;
  int wave = tid >> 6;
  int lane = tid & 63;
  int wm = wave >> 1;   // 0..1 : 64 rows
  int wn = wave & 1;    // 0..1 : 64 cols
  const int c = lane & 15;
  const int q = lane >> 4;

  const int* listE = list + e * NTOK;

  // Staging: each inst covers 8 rows x 8 granules (1 KB). Lane l -> row
  // +(l>>3), LDS slot l&7; fetches global granule (l&7)^(l>>3) so that LDS
  // slot s of row r holds granule s^(r&7)  (bases are multiples of 8).
  int rloc = lane >> 3;
  int gglob = (lane & 7) ^ rloc;
  const ushort* aptr[4];
  ushort* alds[4];
#pragma unroll
  for (int p = 0; p < 4; ++p) {
    int r = m0 + wave * 32 + p * 8 + rloc;
    int tok = listE[r < M ? r : m0];   // clamp padded rows
    aptr[p] = Db + (size_t)tok * D + gglob * 8;
    alds[p] = &As[(wave * 32 + p * 8) * BK];
  }
  const ushort* WbE = Wb + ((size_t)e << 20);
  const ushort* bptr[4];
  ushort* blds[4];
#pragma unroll
  for (int p = 0; p < 4; ++p) {
    int row = n0 + wave * 32 + p * 8 + rloc;
    bptr[p] = WbE + (size_t)row * D + gglob * 8;
    blds[p] = &Bs[(wave * 32 + p * 8) * BK];
  }

  f32x4 acc[4][4];
#pragma unroll
  for (int i = 0; i < 4; ++i)
#pragma unroll
    for (int j = 0; j < 4; ++j)
      acc[i][j] = (f32x4){0.f, 0.f, 0.f, 0.f};

  for (int k0 = 0; k0 < D; k0 += BK) {
#pragma unroll
    for (int p = 0; p < 4; ++p)
      __builtin_amdgcn_global_load_lds(
          (const __attribute__((address_space(1))) void*)(aptr[p] + k0),
          (__attribute__((address_space(3))) void*)alds[p], 16, 0, 0);
#pragma unroll
    for (int p = 0; p < 4; ++p)
      __builtin_amdgcn_global_load_lds(
          (const __attribute__((address_space(1))) void*)(bptr[p] + k0),
          (__attribute__((address_space(3))) void*)blds[p], 16, 0, 0);
    __syncthreads();

#pragma unroll
    for (int s = 0; s < 2; ++s) {
      // granule g = s*4+q; swizzled slot = g ^ (row&7), row&7 == c&7
      int sw = (((s * 4 + q) ^ (c & 7)) * 8);
      short8 a[4], b[4];
#pragma unroll
      for (int i = 0; i < 4; ++i)
        a[i] = *(const short8*)&As[(wm * 64 + i * 16 + c) * BK + sw];
#pragma unroll
      for (int j = 0; j < 4; ++j)
        b[j] = *(const short8*)&Bs[(wn * 64 + j * 16 + c) * BK + sw];
#pragma unroll
      for (int i = 0; i < 4; ++i)
#pragma unroll
        for (int j = 0; j < 4; ++j)
          acc[i][j] = __builtin_amdgcn_mfma_f32_16x16x32_bf16(a[i], b[j], acc[i][j], 0, 0, 0);
    }
    __syncthreads();
  }

  // Epilogue: C/D layout col=lane&15, row=(lane>>4)*4+reg
  float bias[4];
#pragma unroll
  for (int j = 0; j < 4; ++j)
    bias[j] = eb[e * D + n0 + wn * 64 + j * 16 + c];
  const float* wlE = wlist + e * NTOK;
#pragma unroll
  for (int i = 0; i < 4; ++i) {
#pragma unroll
    for (int r = 0; r < 4; ++r) {
      int m = m0 + wm * 64 + i * 16 + q * 4 + r;
      if (m < M) {
        int tok = listE[m];
        float w = wlE[m];
        float* orow = out + (size_t)tok * D + n0 + wn * 64 + c;
#pragma unroll
        for (int j = 0; j < 4; ++j)
          atomicAdd(&orow[j * 16], (acc[i][j][r] + bias[j]) * w);
      }
    }
  }
}

extern "C" void kernel_launch(void* const* d_in, const int* in_sizes, int n_in,
                              void* d_out, int out_size, void* d_ws, size_t ws_size,
                              hipStream_t stream) {
  const float* input_feat = (const float*)d_in[0];
  const float* delta      = (const float*)d_in[1];
  const float* gate_W     = (const float*)d_in[2];
  const float* gate_b     = (const float*)d_in[3];
  const float* expert_W   = (const float*)d_in[4];
  const float* expert_b   = (const float*)d_in[5];
  float* out = (float*)d_out;

  // ws: Wb 16MiB | Db 16MiB | cnt | list | wlist | idx01 | w01
  char* ws = (char*)d_ws;
  ushort* Wb    = (ushort*)ws;
  ushort* Db    = (ushort*)(ws + 16777216);
  char*   meta  = ws + 2 * 16777216;
  int*    cnt   = (int*)meta;
  int*    list  = (int*)(meta + 256);
  float*  wlist = (float*)(meta + 256 + NTOK * E * 4);
  int*    idx01 = (int*)(meta + 256 + 2 * NTOK * E * 4);
  float2* w01   = (float2*)(meta + 256 + 2 * NTOK * E * 4 + NTOK * 4);

  fused_pre_kernel<<<CONV_BLOCKS + GATE_BLOCKS, 256, 0, stream>>>(
      expert_W, delta, input_feat, gate_W, gate_b, Wb, Db, out, cnt, idx01, w01);
  bin_kernel<<<NTOK / 256, 256, 0, stream>>>(idx01, w01, cnt, list, wlist);
  moe_gemm_kernel<<<(NTOK / BM) * 64, 256, 0, stream>>>(
      Db, Wb, expert_b, cnt, list, wlist, out);
}